// Round 6
// baseline (27.672 us; speedup 1.0000x reference)
//
#include <hip/hip_runtime.h>

#define GTCR_EPS 0.001f
#define GTCR_D 4096

// Kernel 1: 2048 blocks x 256 threads; one row per WAVE (4 rows/block).
// Row = 1024 float4; lane reads 16 float4 (lane + 64k), ALL issued before
// any FMA (static-index array -> registers, no scratch). Wave shuffle-reduce,
// log1p on lane 0, block LDS-sum, one plain store per block.
__global__ __launch_bounds__(256, 4) void gtcr_row_kernel(
    const float* __restrict__ z, float* __restrict__ partial, float lmbd) {
    const int wid  = threadIdx.x >> 6;   // wave 0..3
    const int lane = threadIdx.x & 63;
    const int row  = blockIdx.x * 4 + wid;

    const float4* zr = reinterpret_cast<const float4*>(z) + (size_t)row * (GTCR_D / 4);

    float4 v[16];
    #pragma unroll
    for (int k = 0; k < 16; ++k)
        v[k] = zr[lane + 64 * k];        // 16 independent 16B loads in flight

    float s0 = 0.0f, s1 = 0.0f, s2 = 0.0f, s3 = 0.0f;
    #pragma unroll
    for (int k = 0; k < 16; k += 4) {
        s0 = fmaf(v[k+0].x, v[k+0].x, fmaf(v[k+0].y, v[k+0].y, fmaf(v[k+0].z, v[k+0].z, fmaf(v[k+0].w, v[k+0].w, s0))));
        s1 = fmaf(v[k+1].x, v[k+1].x, fmaf(v[k+1].y, v[k+1].y, fmaf(v[k+1].z, v[k+1].z, fmaf(v[k+1].w, v[k+1].w, s1))));
        s2 = fmaf(v[k+2].x, v[k+2].x, fmaf(v[k+2].y, v[k+2].y, fmaf(v[k+2].z, v[k+2].z, fmaf(v[k+2].w, v[k+2].w, s2))));
        s3 = fmaf(v[k+3].x, v[k+3].x, fmaf(v[k+3].y, v[k+3].y, fmaf(v[k+3].z, v[k+3].z, fmaf(v[k+3].w, v[k+3].w, s3))));
    }
    float s = (s0 + s1) + (s2 + s3);

    // Wave-64 shuffle reduction: full row sum lands in lane 0.
    #pragma unroll
    for (int off = 32; off > 0; off >>= 1)
        s += __shfl_down(s, off, 64);

    __shared__ float wres[4];
    if (lane == 0) wres[wid] = log1pf(lmbd * s);
    __syncthreads();

    if (threadIdx.x == 0)
        partial[blockIdx.x] = (wres[0] + wres[1]) + (wres[2] + wres[3]);
}

// Kernel 2: ONE wave reduces 2048 partials (512 float4, 8 per lane).
// No LDS, no __syncthreads — pure shuffle reduce.
__global__ __launch_bounds__(64) void gtcr_final_kernel(
    const float* __restrict__ partial, float* __restrict__ out, float scale) {
    const float4* p4 = reinterpret_cast<const float4*>(partial);
    const int lane = threadIdx.x;

    float4 v[8];
    #pragma unroll
    for (int k = 0; k < 8; ++k)
        v[k] = p4[lane + 64 * k];

    float s = 0.0f;
    #pragma unroll
    for (int k = 0; k < 8; ++k)
        s += ((v[k].x + v[k].y) + (v[k].z + v[k].w));

    #pragma unroll
    for (int off = 32; off > 0; off >>= 1)
        s += __shfl_down(s, off, 64);

    if (lane == 0)
        out[0] = scale * s;   // scale = -0.5 / B
}

extern "C" void kernel_launch(void* const* d_in, const int* in_sizes, int n_in,
                              void* d_out, int out_size, void* d_ws, size_t ws_size,
                              hipStream_t stream) {
    const float* z = (const float*)d_in[0];
    float* out = (float*)d_out;
    float* partial = (float*)d_ws;               // 2048 floats, fully overwritten

    const int B = in_sizes[0] / GTCR_D;          // 8192
    const int nblocks = B / 4;                   // 2048
    const float lmbd = (float)GTCR_D * ((float)B * GTCR_EPS);  // 33554.432

    gtcr_row_kernel<<<nblocks, 256, 0, stream>>>(z, partial, lmbd);
    gtcr_final_kernel<<<1, 64, 0, stream>>>(partial, out, -0.5f / (float)B);
}